// Round 2
// baseline (687.787 us; speedup 1.0000x reference)
//
#include <hip/hip_runtime.h>
#include <math.h>

// SelfAttentionRouter: B=16384, CAPS=32, FEAT=256, fp32.
// out[b,j] = sum_i x[b,i,j] * (softmax_i(scores)[b,i] + bias[i,j])
// scores[b,i] = (1/16) * sum_j x[b,i,j] * colsum[b,j],  colsum[b,j] = sum_k x[b,k,j]
//
// Layout: 256 threads = 4 waves. Wave w owns feature stripe [64w, 64w+64).
// Lane = (ci, fi): ci = lane>>4 owns caps [8ci, 8ci+8); fi = lane&15 owns
// float4 group g = 16w + fi. Per thread: 8 x float4 = the full element held
// across the block in registers; single HBM read.
//
// Cross-wave traffic: ONLY the 32 partial scores (512 B LDS), one barrier per
// element, double-buffered so no trailing barrier. Barrier waits lgkmcnt only
// (raw s_barrier) so prefetched global loads for the NEXT element stay in
// flight across it (hipcc's __syncthreads would drain vmcnt(0) — m97).

constexpr int CAPS = 32;
constexpr int FEAT = 256;
constexpr int F4   = FEAT / 4;   // 64 float4 per cap row
constexpr int NBLK = 2048;

__global__ __launch_bounds__(256, 4)
void router_kernel(const float* __restrict__ inp,
                   const float* __restrict__ bias,
                   float* __restrict__ out, int batch) {
    const int t    = threadIdx.x;
    const int w    = t >> 6;          // wave id -> feature stripe
    const int lane = t & 63;
    const int ci   = lane >> 4;       // cap group: caps [8ci, 8ci+8)
    const int fi   = lane & 15;
    const int g    = w * 16 + fi;     // float4 column index (0..63)
    const int c    = lane & 31;       // cap this lane handles in softmax

    __shared__ float pscore[2][4][CAPS];   // [elem parity][wave][cap]

    const float4* inp4  = reinterpret_cast<const float4*>(inp);
    const float4* bias4 = reinterpret_cast<const float4*>(bias);

    // per-lane row offsets into a 512-float4 element tile
    int rowoff[8];
    #pragma unroll
    for (int il = 0; il < 8; ++il) rowoff[il] = (8 * ci + il) * F4 + g;

    const int G = gridDim.x;

    auto process = [&](float4 (&x)[8], int b, int buf) {
        // ---- colsum: in-lane over 8 caps, then butterfly over ci (xor 16,32) ----
        float4 cs = x[0];
        #pragma unroll
        for (int il = 1; il < 8; ++il) {
            cs.x += x[il].x; cs.y += x[il].y; cs.z += x[il].z; cs.w += x[il].w;
        }
        #pragma unroll
        for (int m = 16; m <= 32; m <<= 1) {
            cs.x += __shfl_xor(cs.x, m, 64);
            cs.y += __shfl_xor(cs.y, m, 64);
            cs.z += __shfl_xor(cs.z, m, 64);
            cs.w += __shfl_xor(cs.w, m, 64);
        }
        // cs = full colsum for this lane's 4 features

        // ---- partial scores for my 8 caps over my 4 features ----
        float p[8];
        #pragma unroll
        for (int il = 0; il < 8; ++il)
            p[il] = x[il].x * cs.x + x[il].y * cs.y + x[il].z * cs.z + x[il].w * cs.w;
        // reduce over the 16 fi-lanes (xor 1,2,4,8): wave-stripe partial scores
        #pragma unroll
        for (int m = 1; m <= 8; m <<= 1) {
            #pragma unroll
            for (int il = 0; il < 8; ++il)
                p[il] += __shfl_xor(p[il], m, 64);
        }
        if (fi == 0) {
            float4* dst = reinterpret_cast<float4*>(&pscore[buf][w][ci * 8]);
            dst[0] = make_float4(p[0], p[1], p[2], p[3]);
            dst[1] = make_float4(p[4], p[5], p[6], p[7]);
        }
        // barrier: wait LDS writes only; prefetched global loads stay in flight
        asm volatile("s_waitcnt lgkmcnt(0)" ::: "memory");
        __builtin_amdgcn_s_barrier();
        asm volatile("" ::: "memory");

        // ---- final scores + distributed softmax (cap c on lanes c and c+32) ----
        float s = (pscore[buf][0][c] + pscore[buf][1][c] +
                   pscore[buf][2][c] + pscore[buf][3][c]) * 0.0625f;  // 1/sqrt(256)
        float mx = s;
        #pragma unroll
        for (int m = 1; m <= 16; m <<= 1)
            mx = fmaxf(mx, __shfl_xor(mx, m, 64));
        const float e = __expf(s - mx);
        float tot = e;
        #pragma unroll
        for (int m = 1; m <= 16; m <<= 1)
            tot += __shfl_xor(tot, m, 64);
        const float wgt = e / tot;

        // ---- output: acc over my 8 caps, weight gathered from lane 8ci+il ----
        float4 acc = make_float4(0.f, 0.f, 0.f, 0.f);
        #pragma unroll
        for (int il = 0; il < 8; ++il) {
            const float  wv = __shfl(wgt, ci * 8 + il, 64);
            const float4 bv = bias4[rowoff[il]];
            acc.x += x[il].x * (wv + bv.x);
            acc.y += x[il].y * (wv + bv.y);
            acc.z += x[il].z * (wv + bv.z);
            acc.w += x[il].w * (wv + bv.w);
        }
        // reduce over ci groups (xor 16,32), lanes ci==0 store the stripe
        #pragma unroll
        for (int m = 16; m <= 32; m <<= 1) {
            acc.x += __shfl_xor(acc.x, m, 64);
            acc.y += __shfl_xor(acc.y, m, 64);
            acc.z += __shfl_xor(acc.z, m, 64);
            acc.w += __shfl_xor(acc.w, m, 64);
        }
        if (ci == 0)
            reinterpret_cast<float4*>(out + (size_t)b * FEAT)[g] = acc;
    };

    int b = blockIdx.x;
    if (b >= batch) return;

    float4 xa[8], xb[8];
    {
        const float4* src = inp4 + (size_t)b * (CAPS * F4);
        #pragma unroll
        for (int il = 0; il < 8; ++il) xa[il] = src[rowoff[il]];
    }

    for (;;) {
        // A phase: prefetch b+G into xb, process xa
        int b1 = b + G;
        if (b1 < batch) {
            const float4* src = inp4 + (size_t)b1 * (CAPS * F4);
            #pragma unroll
            for (int il = 0; il < 8; ++il) xb[il] = src[rowoff[il]];
        }
        process(xa, b, 0);
        if (b1 >= batch) return;
        b = b1;

        // B phase: prefetch b+G into xa, process xb
        int b2 = b + G;
        if (b2 < batch) {
            const float4* src = inp4 + (size_t)b2 * (CAPS * F4);
            #pragma unroll
            for (int il = 0; il < 8; ++il) xa[il] = src[rowoff[il]];
        }
        process(xb, b, 1);
        if (b2 >= batch) return;
        b = b2;
    }
}

extern "C" void kernel_launch(void* const* d_in, const int* in_sizes, int n_in,
                              void* d_out, int out_size, void* d_ws, size_t ws_size,
                              hipStream_t stream) {
    const float* inp  = reinterpret_cast<const float*>(d_in[0]);
    const float* bias = reinterpret_cast<const float*>(d_in[1]);
    float* out        = reinterpret_cast<float*>(d_out);

    const int batch = in_sizes[0] / (CAPS * FEAT);   // 16384
    const int grid  = (batch < NBLK) ? batch : NBLK;
    router_kernel<<<grid, 256, 0, stream>>>(inp, bias, out, batch);
}